// Round 3
// baseline (810.774 us; speedup 1.0000x reference)
//
#include <hip/hip_runtime.h>
#include <hip/hip_bf16.h>

typedef __hip_bfloat16 bf16;

#define NB   20000   // nodes per graph
#define BATCH 2
#define FDIM 128
#define HDIM 128
#define KNBR 32
#define NCLS 40
#define NLAYER 3

__device__ __forceinline__ float b2f(bf16 x) { return __bfloat162float(x); }

// ---------------- embed: h = (x @ W_embed) / row_sum(x) ----------------
// one node per 128-thread block; thread t computes output feature t
// inputs f32; h stored bf16 (f32 accumulation)
__global__ void embed_kernel(const float* __restrict__ x,
                             const float* __restrict__ W,
                             bf16* __restrict__ h) {
    const int node = blockIdx.x;          // 0 .. B*N-1
    const int t    = threadIdx.x;         // 0 .. 127
    __shared__ float xs[FDIM];
    __shared__ float red[FDIM];

    float xv = x[(size_t)node * FDIM + t];
    xs[t]  = xv;
    red[t] = xv;
    __syncthreads();
    for (int s = 64; s > 0; s >>= 1) {
        if (t < s) red[t] += red[t + s];
        __syncthreads();
    }
    const float inv = 1.0f / red[0];

    float acc = 0.0f;
#pragma unroll 8
    for (int j = 0; j < FDIM; ++j) {
        acc += xs[j] * W[j * HDIM + t];
    }
    h[(size_t)node * HDIM + t] = __float2bfloat16(acc * inv);
}

// ---------------- GCN layer ----------------
// neigh = (sum_k h[idx[k]]) / max(vl,1);  h_out = relu(neigh @ W + h @ B)
__global__ void layer_kernel(const bf16* __restrict__ h_in,
                             const int* __restrict__ nidx,
                             const int* __restrict__ vlen,
                             const float* __restrict__ Wl,
                             const float* __restrict__ Bl,
                             bf16* __restrict__ h_out) {
    const int node = blockIdx.x;          // flat b*N + n
    const int b    = node / NB;
    const int t    = threadIdx.x;
    __shared__ float hn[HDIM];
    __shared__ float ng[HDIM];

    const float hv = b2f(h_in[(size_t)node * HDIM + t]);
    hn[t] = hv;

    // gather-sum over ALL K neighbors (valid_lens is divisor only!)
    const int* ip = nidx + (size_t)node * KNBR;
    const size_t base = (size_t)b * NB;
    float acc = 0.0f;
#pragma unroll 4
    for (int k = 0; k < KNBR; ++k) {
        const int j = ip[k];
        acc += b2f(h_in[(base + j) * HDIM + t]);
    }
    int vl = vlen[node];
    if (vl == 0) vl = 1;
    acc *= (1.0f / (float)vl);
    ng[t] = acc;
    __syncthreads();

    float out = 0.0f;
#pragma unroll 8
    for (int j = 0; j < HDIM; ++j) {
        out += ng[j] * Wl[j * HDIM + t];
        out += hn[j] * Bl[j * HDIM + t];
    }
    h_out[(size_t)node * HDIM + t] = __float2bfloat16(fmaxf(out, 0.0f));
}

// ---------------- classifier + softmax ----------------
__global__ void cls_kernel(const bf16* __restrict__ h,
                           const float* __restrict__ W1,
                           const float* __restrict__ b1,
                           const float* __restrict__ W2,
                           const float* __restrict__ b2,
                           float* __restrict__ out) {
    const int node = blockIdx.x;
    const int t    = threadIdx.x;
    __shared__ float hs[HDIM];
    __shared__ float zs[HDIM];
    __shared__ float lg[NCLS];

    hs[t] = b2f(h[(size_t)node * HDIM + t]);
    __syncthreads();

    float z = b1[t];
#pragma unroll 8
    for (int j = 0; j < HDIM; ++j) {
        z += hs[j] * W1[j * HDIM + t];
    }
    zs[t] = fmaxf(z, 0.0f);
    __syncthreads();

    if (t < NCLS) {
        float l = b2[t];
#pragma unroll 8
        for (int j = 0; j < HDIM; ++j) {
            l += zs[j] * W2[j * NCLS + t];
        }
        lg[t] = l;
    }
    __syncthreads();

    if (t == 0) {
        float m = lg[0];
        for (int c = 1; c < NCLS; ++c) m = fmaxf(m, lg[c]);
        float s = 0.0f;
        for (int c = 0; c < NCLS; ++c) { float e = expf(lg[c] - m); lg[c] = e; s += e; }
        const float inv = 1.0f / s;
        for (int c = 0; c < NCLS; ++c) lg[c] *= inv;
    }
    __syncthreads();

    if (t < NCLS) out[(size_t)node * NCLS + t] = lg[t];
}

extern "C" void kernel_launch(void* const* d_in, const int* in_sizes, int n_in,
                              void* d_out, int out_size, void* d_ws, size_t ws_size,
                              hipStream_t stream) {
    const float* x    = (const float*)d_in[0];  // [B,N,F]
    const int*  nidx  = (const int*)  d_in[1];  // [B,N,K]
    const int*  vlen  = (const int*)  d_in[2];  // [B,N]
    const float* Wemb = (const float*)d_in[3];  // [F,H]
    const float* gW   = (const float*)d_in[4];  // [L,H,H]
    const float* gB   = (const float*)d_in[5];  // [L,H,H]
    const float* W1   = (const float*)d_in[6];  // [H,H]
    const float* b1   = (const float*)d_in[7];  // [H]
    const float* W2   = (const float*)d_in[8];  // [H,C]
    const float* b2   = (const float*)d_in[9];  // [C]
    float* out = (float*)d_out;

    const int nodes = BATCH * NB;
    bf16* h0 = (bf16*)d_ws;
    bf16* h1 = h0 + (size_t)nodes * HDIM;

    embed_kernel<<<nodes, 128, 0, stream>>>(x, Wemb, h0);

    for (int l = 0; l < NLAYER; ++l) {
        layer_kernel<<<nodes, 128, 0, stream>>>(h0, nidx, vlen,
                                                gW + (size_t)l * HDIM * HDIM,
                                                gB + (size_t)l * HDIM * HDIM,
                                                h1);
        bf16* tmp = h0; h0 = h1; h1 = tmp;
    }

    cls_kernel<<<nodes, 128, 0, stream>>>(h0, W1, b1, W2, b2, out);
}

// Round 4
// 221.940 us; speedup vs baseline: 3.6531x; 3.6531x over previous
//
#include <hip/hip_runtime.h>
#include <hip/hip_bf16.h>

typedef __hip_bfloat16 bf16;
typedef __attribute__((ext_vector_type(8))) short short8;
typedef __attribute__((ext_vector_type(4))) float f32x4;

#define NB    20000
#define BATCH 2
#define HDIM  128
#define KNBR  32
#define NCLS  40
#define NLAYER 3
#define BM    32          // rows (nodes) per block tile
#define NGLD  136         // padded LDS row stride (bf16 elems), 272 B, 16B-aligned rows

__device__ __forceinline__ short f2bf(float v) {
    return __builtin_bit_cast(short, __float2bfloat16(v));
}
__device__ __forceinline__ float blo(unsigned u) { return __builtin_bit_cast(float, u << 16); }
__device__ __forceinline__ float bhi(unsigned u) { return __builtin_bit_cast(float, u & 0xffff0000u); }

// B-operand fragment from global f32 row-major [K][ldn]: lane holds
// B[kbase + j][col], j=0..7, where caller passes kbase = q*32 + quad*8, col = nbase + (lane&15)
__device__ __forceinline__ short8 load_bfrag(const float* __restrict__ W, int ldn,
                                             int kbase, int col, bool valid) {
    short8 r;
#pragma unroll
    for (int j = 0; j < 8; ++j) {
        float v = valid ? W[(kbase + j) * ldn + col] : 0.0f;
        r[j] = f2bf(v);
    }
    return r;
}

// A-operand fragment from global f32 row-major (convert to bf16)
__device__ __forceinline__ short8 load_afrag_f32(const float* __restrict__ p) {
    short8 r;
#pragma unroll
    for (int j = 0; j < 8; ++j) r[j] = f2bf(p[j]);
    return r;
}

// ---------------- rowsum: rs[r] = 1 / sum(x[r,:]) ----------------
// 8 lanes per row, 32 rows per 256-thread block
__global__ void rowsum_kernel(const float* __restrict__ x, float* __restrict__ rs) {
    const int t = threadIdx.x;
    const int r = blockIdx.x * 32 + (t >> 3);
    const float4* p = (const float4*)(x + (size_t)r * HDIM + (t & 7) * 16);
    float s = 0.0f;
#pragma unroll
    for (int i = 0; i < 4; ++i) {
        float4 v = p[i];
        s += v.x + v.y + v.z + v.w;
    }
    s += __shfl_xor(s, 1, 8);
    s += __shfl_xor(s, 2, 8);
    s += __shfl_xor(s, 4, 8);
    if ((t & 7) == 0) rs[r] = 1.0f / s;
}

// ---------------- embed GEMM: h0 = (x @ Wemb) * rs ----------------
__global__ __launch_bounds__(256, 2) void embed_gemm(const float* __restrict__ x,
                                                     const float* __restrict__ W,
                                                     const float* __restrict__ rs,
                                                     bf16* __restrict__ h0) {
    const int t = threadIdx.x;
    const int row0 = blockIdx.x * BM;
    const int w = t >> 6, l = t & 63;
    const int m16 = l & 15, quad = l >> 4;
    const int ncol0 = w * 32;

    short8 wf[2][4];
#pragma unroll
    for (int nt = 0; nt < 2; ++nt) {
        const int col = ncol0 + nt * 16 + m16;
#pragma unroll
        for (int q = 0; q < 4; ++q)
            wf[nt][q] = load_bfrag(W, HDIM, q * 32 + quad * 8, col, true);
    }

    f32x4 acc[2][2] = {};
#pragma unroll
    for (int q = 0; q < 4; ++q) {
        short8 a[2];
#pragma unroll
        for (int mt = 0; mt < 2; ++mt)
            a[mt] = load_afrag_f32(x + (size_t)(row0 + mt * 16 + m16) * HDIM + q * 32 + quad * 8);
#pragma unroll
        for (int mt = 0; mt < 2; ++mt)
#pragma unroll
            for (int nt = 0; nt < 2; ++nt)
                acc[mt][nt] = __builtin_amdgcn_mfma_f32_16x16x32_bf16(a[mt], wf[nt][q], acc[mt][nt], 0, 0, 0);
    }

#pragma unroll
    for (int mt = 0; mt < 2; ++mt)
#pragma unroll
        for (int r = 0; r < 4; ++r) {
            const int rr = row0 + mt * 16 + quad * 4 + r;
            const float inv = rs[rr];
#pragma unroll
            for (int nt = 0; nt < 2; ++nt) {
                const int cc = ncol0 + nt * 16 + m16;
                h0[(size_t)rr * HDIM + cc] = __float2bfloat16(acc[mt][nt][r] * inv);
            }
        }
}

// ---------------- GCN layer: h_out = relu(NG@W + H@B) ----------------
__global__ __launch_bounds__(256, 2) void layer_gemm(const bf16* __restrict__ h_in,
                                                     const int* __restrict__ nidx,
                                                     const int* __restrict__ vlen,
                                                     const float* __restrict__ Wl,
                                                     const float* __restrict__ Bl,
                                                     bf16* __restrict__ h_out) {
    __shared__ int   sidx[BM * KNBR];     // 4 KB
    __shared__ short sng[BM * NGLD];      // 8.7 KB, bf16 bits
    const int t = threadIdx.x;
    const int row0 = blockIdx.x * BM;

    // stage neighbor indices (1024 ints, coalesced int4)
    ((int4*)sidx)[t] = ((const int4*)(nidx + (size_t)row0 * KNBR))[t];
    __syncthreads();

    // ---- gather: 8 threads per node, 16 features each ----
    {
        const int node = t >> 3;
        const int fs = (t & 7) * 16;
        const int g = row0 + node;
        const bf16* hb = h_in + (size_t)((g / NB) * NB) * HDIM;
        float acc[16];
#pragma unroll
        for (int i = 0; i < 16; ++i) acc[i] = 0.0f;
        const int* ip = sidx + node * KNBR;
        for (int k = 0; k < KNBR; ++k) {
            const uint4* p = (const uint4*)(hb + (size_t)ip[k] * HDIM + fs);
            uint4 u0 = p[0], u1 = p[1];
            acc[0] += blo(u0.x);  acc[1] += bhi(u0.x);
            acc[2] += blo(u0.y);  acc[3] += bhi(u0.y);
            acc[4] += blo(u0.z);  acc[5] += bhi(u0.z);
            acc[6] += blo(u0.w);  acc[7] += bhi(u0.w);
            acc[8] += blo(u1.x);  acc[9] += bhi(u1.x);
            acc[10] += blo(u1.y); acc[11] += bhi(u1.y);
            acc[12] += blo(u1.z); acc[13] += bhi(u1.z);
            acc[14] += blo(u1.w); acc[15] += bhi(u1.w);
        }
        int vl = vlen[g]; if (vl == 0) vl = 1;
        const float inv = 1.0f / (float)vl;
        unsigned* dst = (unsigned*)sng + (node * NGLD + fs) / 2;
#pragma unroll
        for (int i = 0; i < 8; ++i) {
            unsigned lo = (unsigned)(unsigned short)f2bf(acc[2 * i] * inv);
            unsigned hi = (unsigned)(unsigned short)f2bf(acc[2 * i + 1] * inv);
            dst[i] = lo | (hi << 16);
        }
    }
    __syncthreads();

    // ---- MFMA: acc = NG@W + H@B ----
    const int w = t >> 6, l = t & 63;
    const int m16 = l & 15, quad = l >> 4;
    const int ncol0 = w * 32;

    short8 wf[2][2][4];   // [matrix][ntile][kstep]
#pragma unroll
    for (int nt = 0; nt < 2; ++nt) {
        const int col = ncol0 + nt * 16 + m16;
#pragma unroll
        for (int q = 0; q < 4; ++q) {
            const int kb = q * 32 + quad * 8;
            wf[0][nt][q] = load_bfrag(Wl, HDIM, kb, col, true);
            wf[1][nt][q] = load_bfrag(Bl, HDIM, kb, col, true);
        }
    }

    f32x4 acc[2][2] = {};
#pragma unroll
    for (int q = 0; q < 4; ++q) {
        short8 aN[2], aH[2];
#pragma unroll
        for (int mt = 0; mt < 2; ++mt) {
            aN[mt] = *(const short8*)(sng + (mt * 16 + m16) * NGLD + q * 32 + quad * 8);
            aH[mt] = *(const short8*)(h_in + (size_t)(row0 + mt * 16 + m16) * HDIM + q * 32 + quad * 8);
        }
#pragma unroll
        for (int mt = 0; mt < 2; ++mt)
#pragma unroll
            for (int nt = 0; nt < 2; ++nt) {
                acc[mt][nt] = __builtin_amdgcn_mfma_f32_16x16x32_bf16(aN[mt], wf[0][nt][q], acc[mt][nt], 0, 0, 0);
                acc[mt][nt] = __builtin_amdgcn_mfma_f32_16x16x32_bf16(aH[mt], wf[1][nt][q], acc[mt][nt], 0, 0, 0);
            }
    }

#pragma unroll
    for (int mt = 0; mt < 2; ++mt)
#pragma unroll
        for (int nt = 0; nt < 2; ++nt)
#pragma unroll
            for (int r = 0; r < 4; ++r) {
                const int rr = row0 + mt * 16 + quad * 4 + r;
                const int cc = ncol0 + nt * 16 + m16;
                h_out[(size_t)rr * HDIM + cc] = __float2bfloat16(fmaxf(acc[mt][nt][r], 0.0f));
            }
}

// ---------------- classifier: softmax(relu(h@W1+b1)@W2 + b2) ----------------
__global__ __launch_bounds__(256, 2) void cls_gemm(const bf16* __restrict__ h,
                                                   const float* __restrict__ W1,
                                                   const float* __restrict__ b1,
                                                   const float* __restrict__ W2,
                                                   const float* __restrict__ b2,
                                                   float* __restrict__ out) {
    __shared__ short sz[BM * NGLD];       // z tile, bf16 bits
    __shared__ float lg[BM * 48];         // logits (padded to 48)
    const int t = threadIdx.x;
    const int row0 = blockIdx.x * BM;
    const int w = t >> 6, l = t & 63;
    const int m16 = l & 15, quad = l >> 4;

    // ---- stage 1: z = relu(h @ W1 + b1) -> LDS ----
    {
        const int ncol0 = w * 32;
        short8 wf[2][4];
#pragma unroll
        for (int nt = 0; nt < 2; ++nt) {
            const int col = ncol0 + nt * 16 + m16;
#pragma unroll
            for (int q = 0; q < 4; ++q)
                wf[nt][q] = load_bfrag(W1, HDIM, q * 32 + quad * 8, col, true);
        }
        f32x4 acc[2][2] = {};
#pragma unroll
        for (int q = 0; q < 4; ++q) {
            short8 a[2];
#pragma unroll
            for (int mt = 0; mt < 2; ++mt)
                a[mt] = *(const short8*)(h + (size_t)(row0 + mt * 16 + m16) * HDIM + q * 32 + quad * 8);
#pragma unroll
            for (int mt = 0; mt < 2; ++mt)
#pragma unroll
                for (int nt = 0; nt < 2; ++nt)
                    acc[mt][nt] = __builtin_amdgcn_mfma_f32_16x16x32_bf16(a[mt], wf[nt][q], acc[mt][nt], 0, 0, 0);
        }
#pragma unroll
        for (int mt = 0; mt < 2; ++mt)
#pragma unroll
            for (int nt = 0; nt < 2; ++nt) {
                const int cc = ncol0 + nt * 16 + m16;
                const float bias = b1[cc];
#pragma unroll
                for (int r = 0; r < 4; ++r) {
                    const int lr = mt * 16 + quad * 4 + r;
                    sz[lr * NGLD + cc] = f2bf(fmaxf(acc[mt][nt][r] + bias, 0.0f));
                }
            }
    }
    __syncthreads();

    // ---- stage 2: logits = z @ W2 + b2 -> LDS (waves 0..2, N=40) ----
    if (w < 3) {
        const int col = w * 16 + m16;
        const bool valid = (col < NCLS);
        short8 wf[4];
#pragma unroll
        for (int q = 0; q < 4; ++q)
            wf[q] = load_bfrag(W2, NCLS, q * 32 + quad * 8, col, valid);
        f32x4 acc[2] = {};
#pragma unroll
        for (int q = 0; q < 4; ++q) {
            short8 a[2];
#pragma unroll
            for (int mt = 0; mt < 2; ++mt)
                a[mt] = *(const short8*)(sz + (mt * 16 + m16) * NGLD + q * 32 + quad * 8);
#pragma unroll
            for (int mt = 0; mt < 2; ++mt)
                acc[mt] = __builtin_amdgcn_mfma_f32_16x16x32_bf16(a[mt], wf[q], acc[mt], 0, 0, 0);
        }
        if (valid) {
            const float bias = b2[col];
#pragma unroll
            for (int mt = 0; mt < 2; ++mt)
#pragma unroll
                for (int r = 0; r < 4; ++r) {
                    const int lr = mt * 16 + quad * 4 + r;
                    lg[lr * 48 + col] = acc[mt][r] + bias;
                }
        }
    }
    __syncthreads();

    // ---- softmax per row (threads 0..31) ----
    if (t < BM) {
        float* row = lg + t * 48;
        float m = row[0];
        for (int c = 1; c < NCLS; ++c) m = fmaxf(m, row[c]);
        float s = 0.0f;
        for (int c = 0; c < NCLS; ++c) { float e = expf(row[c] - m); row[c] = e; s += e; }
        const float inv = 1.0f / s;
        for (int c = 0; c < NCLS; ++c) row[c] *= inv;
    }
    __syncthreads();

    // ---- store 32x40 f32, coalesced ----
    for (int i = t; i < BM * NCLS; i += 256) {
        const int r = i / NCLS, c = i - r * NCLS;
        out[(size_t)row0 * NCLS + i] = lg[r * 48 + c];
    }
}

extern "C" void kernel_launch(void* const* d_in, const int* in_sizes, int n_in,
                              void* d_out, int out_size, void* d_ws, size_t ws_size,
                              hipStream_t stream) {
    const float* x    = (const float*)d_in[0];
    const int*  nidx  = (const int*)  d_in[1];
    const int*  vlen  = (const int*)  d_in[2];
    const float* Wemb = (const float*)d_in[3];
    const float* gW   = (const float*)d_in[4];
    const float* gB   = (const float*)d_in[5];
    const float* W1   = (const float*)d_in[6];
    const float* b1   = (const float*)d_in[7];
    const float* W2   = (const float*)d_in[8];
    const float* b2   = (const float*)d_in[9];
    float* out = (float*)d_out;

    const int nodes = BATCH * NB;           // 40000
    const int tiles = nodes / BM;           // 1250
    bf16* h0 = (bf16*)d_ws;
    bf16* h1 = h0 + (size_t)nodes * HDIM;
    float* rs = (float*)h1;  // transient: consumed by embed_gemm before layer 1 writes h1

    rowsum_kernel<<<tiles, 256, 0, stream>>>(x, rs);
    embed_gemm<<<tiles, 256, 0, stream>>>(x, Wemb, rs, h0);

    for (int lyr = 0; lyr < NLAYER; ++lyr) {
        layer_gemm<<<tiles, 256, 0, stream>>>(h0, nidx, vlen,
                                              gW + (size_t)lyr * HDIM * HDIM,
                                              gB + (size_t)lyr * HDIM * HDIM,
                                              h1);
        bf16* tmp = h0; h0 = h1; h1 = tmp;
    }

    cls_gemm<<<tiles, 256, 0, stream>>>(h0, W1, b1, W2, b2, out);
}

// Round 5
// 212.224 us; speedup vs baseline: 3.8204x; 1.0458x over previous
//
#include <hip/hip_runtime.h>
#include <hip/hip_bf16.h>

typedef __hip_bfloat16 bf16;
typedef __attribute__((ext_vector_type(8))) short short8;
typedef __attribute__((ext_vector_type(4))) float f32x4;

#define NB    20000
#define BATCH 2
#define HDIM  128
#define KNBR  32
#define NCLS  40
#define NLAYER 3
#define BM    64          // rows (nodes) per block tile
#define LDP   136         // padded LDS row stride (bf16 elems): 272 B, 16B-aligned

__device__ __forceinline__ short f2bf(float v) {
    return __builtin_bit_cast(short, __float2bfloat16(v));
}
__device__ __forceinline__ float blo(unsigned u) { return __builtin_bit_cast(float, u << 16); }
__device__ __forceinline__ float bhi(unsigned u) { return __builtin_bit_cast(float, u & 0xffff0000u); }

// ---------------- weight pre-pack: f32 [K][N] -> bf16 fragment layout ----------------
// dst[((k>>3)*N + n)*8 + (k&7)] so a B-fragment (q,quad,col) is one contiguous 16B load.
// m=0: Wemb, m=1..3: gW[l], m=4..6: gB[l], m=7: W1 (all 128x128), then W2 (128x40).
__global__ void pack_weights(const float* __restrict__ Wemb, const float* __restrict__ gW,
                             const float* __restrict__ gB, const float* __restrict__ W1,
                             const float* __restrict__ W2, short* __restrict__ pw) {
    const int idx = blockIdx.x * 256 + threadIdx.x;
    if (idx < 8 * 16384) {
        const int m = idx >> 14, e = idx & 16383;
        const float* src = (m == 0) ? Wemb
                         : (m <= 3) ? gW + (size_t)(m - 1) * 16384
                         : (m <= 6) ? gB + (size_t)(m - 4) * 16384
                         : W1;
        const int k = e >> 7, n = e & 127;
        pw[m * 16384 + (((k >> 3) * 128 + n) << 3) + (k & 7)] = f2bf(src[e]);
    } else {
        const int e = idx - 8 * 16384;
        if (e < 128 * NCLS) {
            const int k = e / NCLS, n = e - k * NCLS;
            pw[8 * 16384 + ((k >> 3) * NCLS + n) * 8 + (k & 7)] = f2bf(W2[e]);
        }
    }
}

// ---------------- embed: h0 = (x @ Wemb) / rowsum(x), rowsum via ones-MFMA ----------------
__global__ __launch_bounds__(512, 4) void embed_gemm(const float* __restrict__ x,
                                                     const short* __restrict__ pwE,
                                                     bf16* __restrict__ h0) {
    __shared__ short sx[BM * LDP];
    const int t = threadIdx.x;
    const int row0 = blockIdx.x * BM;

    // stage x tile as bf16 (8 threads/row, 16 feats each)
    {
        const int r = t >> 3, fs = (t & 7) * 16;
        const float4* p = (const float4*)(x + (size_t)(row0 + r) * HDIM + fs);
        float4 v[4];
#pragma unroll
        for (int i = 0; i < 4; ++i) v[i] = p[i];
        const float* vf = (const float*)v;
        unsigned* dst = (unsigned*)(sx + r * LDP + fs);
#pragma unroll
        for (int i = 0; i < 8; ++i) {
            unsigned lo = (unsigned)(unsigned short)f2bf(vf[2 * i]);
            unsigned hi = (unsigned)(unsigned short)f2bf(vf[2 * i + 1]);
            dst[i] = lo | (hi << 16);
        }
    }
    __syncthreads();

    const int w = t >> 6, l = t & 63;
    const int m16 = l & 15, quad = l >> 4;
    const int col = w * 16 + m16;

    short8 ones;
#pragma unroll
    for (int j = 0; j < 8; ++j) ones[j] = (short)0x3F80;  // bf16 1.0

    short8 wf[4];
#pragma unroll
    for (int q = 0; q < 4; ++q)
        wf[q] = *(const short8*)(pwE + (((q * 4 + quad) * 128 + col) << 3));

    f32x4 acc[4] = {}, rsum[4] = {};
#pragma unroll
    for (int q = 0; q < 4; ++q)
#pragma unroll
        for (int mt = 0; mt < 4; ++mt) {
            short8 a = *(const short8*)(sx + (mt * 16 + m16) * LDP + q * 32 + quad * 8);
            acc[mt]  = __builtin_amdgcn_mfma_f32_16x16x32_bf16(a, wf[q], acc[mt], 0, 0, 0);
            rsum[mt] = __builtin_amdgcn_mfma_f32_16x16x32_bf16(a, ones,  rsum[mt], 0, 0, 0);
        }

#pragma unroll
    for (int mt = 0; mt < 4; ++mt)
#pragma unroll
        for (int r = 0; r < 4; ++r) {
            const int rr = row0 + mt * 16 + quad * 4 + r;
            h0[(size_t)rr * HDIM + col] = __float2bfloat16(acc[mt][r] / rsum[mt][r]);
        }
}

// ---------------- GCN layer: h_out = relu(NG@W + H@B) ----------------
__global__ __launch_bounds__(512, 4) void layer_gemm(const bf16* __restrict__ h_in,
                                                     const int* __restrict__ nidx,
                                                     const int* __restrict__ vlen,
                                                     const short* __restrict__ pwW,
                                                     const short* __restrict__ pwB,
                                                     bf16* __restrict__ h_out) {
    __shared__ int   sidx[BM * KNBR];   // 8 KB
    __shared__ short sng[BM * LDP];     // 17.4 KB
    __shared__ short sh[BM * LDP];      // 17.4 KB
    const int t = threadIdx.x;
    const int row0 = blockIdx.x * BM;

    // stage neighbor indices (2048 ints via int4) + h tile (bf16 copy)
    ((int4*)sidx)[t] = ((const int4*)(nidx + (size_t)row0 * KNBR))[t];
    {
        const int r = t >> 3, fs = (t & 7) * 16;
        const uint4* p = (const uint4*)(h_in + (size_t)(row0 + r) * HDIM + fs);
        uint4 a = p[0], b = p[1];
        uint4* d = (uint4*)(sh + r * LDP + fs);
        d[0] = a; d[1] = b;
    }
    __syncthreads();

    // ---- gather: 8 threads/node, 16 features each ----
    {
        const int node = t >> 3;
        const int fs = (t & 7) * 16;
        const int g = row0 + node;
        const bf16* hb = h_in + (size_t)((g >= NB) ? NB : 0) * HDIM;
        float acc[16];
#pragma unroll
        for (int i = 0; i < 16; ++i) acc[i] = 0.0f;
        const int* ip = sidx + node * KNBR;
#pragma unroll 4
        for (int k = 0; k < KNBR; ++k) {
            const uint4* p = (const uint4*)(hb + (size_t)ip[k] * HDIM + fs);
            uint4 u0 = p[0], u1 = p[1];
            acc[0] += blo(u0.x);  acc[1] += bhi(u0.x);
            acc[2] += blo(u0.y);  acc[3] += bhi(u0.y);
            acc[4] += blo(u0.z);  acc[5] += bhi(u0.z);
            acc[6] += blo(u0.w);  acc[7] += bhi(u0.w);
            acc[8] += blo(u1.x);  acc[9] += bhi(u1.x);
            acc[10] += blo(u1.y); acc[11] += bhi(u1.y);
            acc[12] += blo(u1.z); acc[13] += bhi(u1.z);
            acc[14] += blo(u1.w); acc[15] += bhi(u1.w);
        }
        int vl = vlen[g]; if (vl == 0) vl = 1;
        const float inv = 1.0f / (float)vl;
        unsigned* dst = (unsigned*)(sng + node * LDP + fs);
#pragma unroll
        for (int i = 0; i < 8; ++i) {
            unsigned lo = (unsigned)(unsigned short)f2bf(acc[2 * i] * inv);
            unsigned hi = (unsigned)(unsigned short)f2bf(acc[2 * i + 1] * inv);
            dst[i] = lo | (hi << 16);
        }
    }
    __syncthreads();

    // ---- MFMA: acc = NG@W + H@B (one 16-col slice per wave) ----
    const int w = t >> 6, l = t & 63;
    const int m16 = l & 15, quad = l >> 4;
    const int col = w * 16 + m16;

    short8 wfW[4], wfB[4];
#pragma unroll
    for (int q = 0; q < 4; ++q) {
        const int off = ((q * 4 + quad) * 128 + col) << 3;
        wfW[q] = *(const short8*)(pwW + off);
        wfB[q] = *(const short8*)(pwB + off);
    }

    f32x4 acc[4] = {};
#pragma unroll
    for (int q = 0; q < 4; ++q)
#pragma unroll
        for (int mt = 0; mt < 4; ++mt) {
            short8 aN = *(const short8*)(sng + (mt * 16 + m16) * LDP + q * 32 + quad * 8);
            short8 aH = *(const short8*)(sh  + (mt * 16 + m16) * LDP + q * 32 + quad * 8);
            acc[mt] = __builtin_amdgcn_mfma_f32_16x16x32_bf16(aN, wfW[q], acc[mt], 0, 0, 0);
            acc[mt] = __builtin_amdgcn_mfma_f32_16x16x32_bf16(aH, wfB[q], acc[mt], 0, 0, 0);
        }

#pragma unroll
    for (int mt = 0; mt < 4; ++mt)
#pragma unroll
        for (int r = 0; r < 4; ++r) {
            const int rr = row0 + mt * 16 + quad * 4 + r;
            h_out[(size_t)rr * HDIM + col] = __float2bfloat16(fmaxf(acc[mt][r], 0.0f));
        }
}

// ---------------- classifier: softmax(relu(h@W1+b1)@W2 + b2) ----------------
__global__ __launch_bounds__(512, 4) void cls_gemm(const bf16* __restrict__ h,
                                                   const short* __restrict__ pwW1,
                                                   const float* __restrict__ b1,
                                                   const short* __restrict__ pwW2,
                                                   const float* __restrict__ b2,
                                                   float* __restrict__ out) {
    __shared__ short sh[BM * LDP];
    __shared__ short sz[BM * LDP];
    __shared__ float lg[BM * 48];
    const int t = threadIdx.x;
    const int row0 = blockIdx.x * BM;

    {
        const int r = t >> 3, fs = (t & 7) * 16;
        const uint4* p = (const uint4*)(h + (size_t)(row0 + r) * HDIM + fs);
        uint4 a = p[0], b = p[1];
        uint4* d = (uint4*)(sh + r * LDP + fs);
        d[0] = a; d[1] = b;
    }
    __syncthreads();

    const int w = t >> 6, l = t & 63;
    const int m16 = l & 15, quad = l >> 4;
    const int col = w * 16 + m16;

    // ---- stage 1: z = relu(h @ W1 + b1) -> LDS ----
    {
        short8 wf[4];
#pragma unroll
        for (int q = 0; q < 4; ++q)
            wf[q] = *(const short8*)(pwW1 + (((q * 4 + quad) * 128 + col) << 3));
        f32x4 acc[4] = {};
#pragma unroll
        for (int q = 0; q < 4; ++q)
#pragma unroll
            for (int mt = 0; mt < 4; ++mt) {
                short8 a = *(const short8*)(sh + (mt * 16 + m16) * LDP + q * 32 + quad * 8);
                acc[mt] = __builtin_amdgcn_mfma_f32_16x16x32_bf16(a, wf[q], acc[mt], 0, 0, 0);
            }
        const float bias = b1[col];
#pragma unroll
        for (int mt = 0; mt < 4; ++mt)
#pragma unroll
            for (int r = 0; r < 4; ++r)
                sz[(mt * 16 + quad * 4 + r) * LDP + col] = f2bf(fmaxf(acc[mt][r] + bias, 0.0f));
    }
    __syncthreads();

    // ---- stage 2: logits = z @ W2 + b2 (waves 0..2 cover 40 cols) ----
    if (w < 3) {
        const bool valid = (col < NCLS);
        short8 wf[4];
#pragma unroll
        for (int q = 0; q < 4; ++q) {
            if (valid) wf[q] = *(const short8*)(pwW2 + (((q * 4 + quad) * NCLS + col) << 3));
            else {
#pragma unroll
                for (int j = 0; j < 8; ++j) wf[q][j] = 0;
            }
        }
        f32x4 acc[4] = {};
#pragma unroll
        for (int q = 0; q < 4; ++q)
#pragma unroll
            for (int mt = 0; mt < 4; ++mt) {
                short8 a = *(const short8*)(sz + (mt * 16 + m16) * LDP + q * 32 + quad * 8);
                acc[mt] = __builtin_amdgcn_mfma_f32_16x16x32_bf16(a, wf[q], acc[mt], 0, 0, 0);
            }
        if (valid) {
            const float bias = b2[col];
#pragma unroll
            for (int mt = 0; mt < 4; ++mt)
#pragma unroll
                for (int r = 0; r < 4; ++r)
                    lg[(mt * 16 + quad * 4 + r) * 48 + col] = acc[mt][r] + bias;
        }
    }
    __syncthreads();

    // ---- softmax per row ----
    if (t < BM) {
        float* row = lg + t * 48;
        float m = row[0];
        for (int c = 1; c < NCLS; ++c) m = fmaxf(m, row[c]);
        float s = 0.0f;
        for (int c = 0; c < NCLS; ++c) { float e = expf(row[c] - m); row[c] = e; s += e; }
        const float inv = 1.0f / s;
        for (int c = 0; c < NCLS; ++c) row[c] *= inv;
    }
    __syncthreads();

    for (int i = t; i < BM * NCLS; i += 512) {
        const int r = i / NCLS, c = i - r * NCLS;
        out[(size_t)row0 * NCLS + i] = lg[r * 48 + c];
    }
}

extern "C" void kernel_launch(void* const* d_in, const int* in_sizes, int n_in,
                              void* d_out, int out_size, void* d_ws, size_t ws_size,
                              hipStream_t stream) {
    const float* x    = (const float*)d_in[0];
    const int*  nidx  = (const int*)  d_in[1];
    const int*  vlen  = (const int*)  d_in[2];
    const float* Wemb = (const float*)d_in[3];
    const float* gW   = (const float*)d_in[4];
    const float* gB   = (const float*)d_in[5];
    const float* W1   = (const float*)d_in[6];
    const float* b1   = (const float*)d_in[7];
    const float* W2   = (const float*)d_in[8];
    const float* b2   = (const float*)d_in[9];
    float* out = (float*)d_out;

    const int nodes = BATCH * NB;           // 40000
    const int tiles = nodes / BM;           // 625
    bf16* h0 = (bf16*)d_ws;
    bf16* h1 = h0 + (size_t)nodes * HDIM;
    short* pw = (short*)(h1 + (size_t)nodes * HDIM);   // 272 KB packed weights
    const short* pwE  = pw;
    const short* pwW1 = pw + 7 * 16384;
    const short* pwW2 = pw + 8 * 16384;

    pack_weights<<<(8 * 16384 + 128 * NCLS + 255) / 256, 256, 0, stream>>>(Wemb, gW, gB, W1, W2, pw);
    embed_gemm<<<tiles, 512, 0, stream>>>(x, pwE, h0);

    for (int lyr = 0; lyr < NLAYER; ++lyr) {
        layer_gemm<<<tiles, 512, 0, stream>>>(h0, nidx, vlen,
                                              pw + (size_t)(1 + lyr) * 16384,
                                              pw + (size_t)(4 + lyr) * 16384,
                                              h1);
        bf16* tmp = h0; h0 = h1; h1 = tmp;
    }

    cls_gemm<<<tiles, 512, 0, stream>>>(h0, pwW1, b1, pwW2, b2, out);
}

// Round 7
// 179.228 us; speedup vs baseline: 4.5237x; 1.1841x over previous
//
#include <hip/hip_runtime.h>
#include <hip/hip_bf16.h>

typedef __hip_bfloat16 bf16;
typedef __attribute__((ext_vector_type(8))) short short8;
typedef __attribute__((ext_vector_type(4))) float f32x4;

#define NB    20000
#define BATCH 2
#define HDIM  128
#define KNBR  32
#define NCLS  40
#define NLAYER 3
#define BM    64          // rows (nodes) per block tile
#define LDP   136         // padded LDS row stride (bf16 elems): 272 B, 16B-aligned
#define NTILES 625        // flattened tiles over 40000 nodes
#define LGRID  632        // 79*8, batch-XCD swizzled with guards

__device__ __forceinline__ short f2bf(float v) {
    return __builtin_bit_cast(short, __float2bfloat16(v));
}
__device__ __forceinline__ float blo(unsigned u) { return __builtin_bit_cast(float, u << 16); }
__device__ __forceinline__ float bhi(unsigned u) { return __builtin_bit_cast(float, u & 0xffff0000u); }

// ---------------- weight pre-pack: f32 [K][N] -> bf16 fragment layout ----------------
// dst[((k>>3)*N + n)*8 + (k&7)] so a B-fragment (q,quad,col) is one contiguous 16B load.
// m=0: Wemb, m=1..3: gW[l], m=4..6: gB[l], m=7: W1 (all 128x128), then W2 (128x40).
__global__ void pack_weights(const float* __restrict__ Wemb, const float* __restrict__ gW,
                             const float* __restrict__ gB, const float* __restrict__ W1,
                             const float* __restrict__ W2, short* __restrict__ pw) {
    const int idx = blockIdx.x * 256 + threadIdx.x;
    if (idx < 8 * 16384) {
        const int m = idx >> 14, e = idx & 16383;
        const float* src = (m == 0) ? Wemb
                         : (m <= 3) ? gW + (size_t)(m - 1) * 16384
                         : (m <= 6) ? gB + (size_t)(m - 4) * 16384
                         : W1;
        const int k = e >> 7, n = e & 127;
        pw[m * 16384 + (((k >> 3) * 128 + n) << 3) + (k & 7)] = f2bf(src[e]);
    } else {
        const int e = idx - 8 * 16384;
        if (e < 128 * NCLS) {
            const int k = e / NCLS, n = e - k * NCLS;
            pw[8 * 16384 + ((k >> 3) * NCLS + n) * 8 + (k & 7)] = f2bf(W2[e]);
        }
    }
}

// ---------------- embed: h0 = (x @ Wemb) / rowsum(x), rowsum via ones-MFMA ----------------
__global__ __launch_bounds__(512, 4) void embed_gemm(const float* __restrict__ x,
                                                     const short* __restrict__ pwE,
                                                     bf16* __restrict__ h0) {
    __shared__ short sx[BM * LDP];
    const int t = threadIdx.x;
    const int row0 = blockIdx.x * BM;

    {
        const int r = t >> 3, fs = (t & 7) * 16;
        const float4* p = (const float4*)(x + (size_t)(row0 + r) * HDIM + fs);
        float4 v[4];
#pragma unroll
        for (int i = 0; i < 4; ++i) v[i] = p[i];
        const float* vf = (const float*)v;
        unsigned* dst = (unsigned*)(sx + r * LDP + fs);
#pragma unroll
        for (int i = 0; i < 8; ++i) {
            unsigned lo = (unsigned)(unsigned short)f2bf(vf[2 * i]);
            unsigned hi = (unsigned)(unsigned short)f2bf(vf[2 * i + 1]);
            dst[i] = lo | (hi << 16);
        }
    }
    __syncthreads();

    const int w = t >> 6, l = t & 63;
    const int m16 = l & 15, quad = l >> 4;
    const int col = w * 16 + m16;

    short8 ones;
#pragma unroll
    for (int j = 0; j < 8; ++j) ones[j] = (short)0x3F80;  // bf16 1.0

    short8 wf[4];
#pragma unroll
    for (int q = 0; q < 4; ++q)
        wf[q] = *(const short8*)(pwE + (((q * 4 + quad) * 128 + col) << 3));

    f32x4 acc[4] = {}, rsum[4] = {};
#pragma unroll
    for (int q = 0; q < 4; ++q)
#pragma unroll
        for (int mt = 0; mt < 4; ++mt) {
            short8 a = *(const short8*)(sx + (mt * 16 + m16) * LDP + q * 32 + quad * 8);
            acc[mt]  = __builtin_amdgcn_mfma_f32_16x16x32_bf16(a, wf[q], acc[mt], 0, 0, 0);
            rsum[mt] = __builtin_amdgcn_mfma_f32_16x16x32_bf16(a, ones,  rsum[mt], 0, 0, 0);
        }

#pragma unroll
    for (int mt = 0; mt < 4; ++mt)
#pragma unroll
        for (int r = 0; r < 4; ++r) {
            const int rr = row0 + mt * 16 + quad * 4 + r;
            h0[(size_t)rr * HDIM + col] = __float2bfloat16(acc[mt][r] / rsum[mt][r]);
        }
}

// ---------------- GCN layer: h_out = relu(NG@W + H@B) ----------------
// Flattened tiles 0..624.  XCD swizzle: slot = blockIdx&7, half = slot>>2,
// idx = (blockIdx>>3)*4 + (slot&3).  Half 0 (XCDs 0-3 under round-robin)
// covers tiles 0..312 (mostly batch 0), half 1 covers 313..624 (batch 1).
// Tile 312 straddles the batch boundary -> per-node batch base in gather.
__global__ __launch_bounds__(512, 4) void layer_gemm(const bf16* __restrict__ h_in,
                                                     const int* __restrict__ nidx,
                                                     const int* __restrict__ vlen,
                                                     const short* __restrict__ pwW,
                                                     const short* __restrict__ pwB,
                                                     bf16* __restrict__ h_out) {
    __shared__ int   sidx[BM * KNBR];   // 8 KB
    __shared__ short sng[BM * LDP];     // 17.4 KB
    __shared__ short sh[BM * LDP];      // 17.4 KB

    const int slot = blockIdx.x & 7;
    const int half = slot >> 2;
    const int idx  = (blockIdx.x >> 3) * 4 + (slot & 3);
    int tile;
    if (half == 0) { if (idx > 312) return; tile = idx; }
    else           { if (idx > 311) return; tile = idx + 313; }

    const int t = threadIdx.x;
    const int row0 = tile * BM;

    // stage neighbor indices (2048 ints via int4) + own h tile (bf16 copy)
    ((int4*)sidx)[t] = ((const int4*)(nidx + (size_t)row0 * KNBR))[t];
    {
        const int r = t >> 3, fs = (t & 7) * 16;
        const uint4* p = (const uint4*)(h_in + (size_t)(row0 + r) * HDIM + fs);
        uint4 a = p[0], b = p[1];
        uint4* d = (uint4*)(sh + r * LDP + fs);
        d[0] = a; d[1] = b;
    }
    __syncthreads();

    // ---- gather in two feature phases: 8 threads/node, 8 features each ----
    {
        const int node = t >> 3;
        const int fs8 = (t & 7) * 8;
        const int g = row0 + node;
        const bf16* hb = h_in + (size_t)((g >= NB) ? NB : 0) * HDIM;
        const int* ip = sidx + node * KNBR;
        int vl = vlen[g]; if (vl == 0) vl = 1;
        const float inv = 1.0f / (float)vl;

#pragma unroll
        for (int fh = 0; fh < 2; ++fh) {
            const int fs = fh * 64 + fs8;
            float acc[8];
#pragma unroll
            for (int i = 0; i < 8; ++i) acc[i] = 0.0f;
#pragma unroll 4
            for (int k = 0; k < KNBR; ++k) {
                const uint4 u = *(const uint4*)(hb + (size_t)ip[k] * HDIM + fs);
                acc[0] += blo(u.x); acc[1] += bhi(u.x);
                acc[2] += blo(u.y); acc[3] += bhi(u.y);
                acc[4] += blo(u.z); acc[5] += bhi(u.z);
                acc[6] += blo(u.w); acc[7] += bhi(u.w);
            }
            unsigned* dst = (unsigned*)(sng + node * LDP + fs);
#pragma unroll
            for (int i = 0; i < 4; ++i) {
                unsigned lo = (unsigned)(unsigned short)f2bf(acc[2 * i] * inv);
                unsigned hi = (unsigned)(unsigned short)f2bf(acc[2 * i + 1] * inv);
                dst[i] = lo | (hi << 16);
            }
            __syncthreads();   // phase alignment keeps L2 working set tight
        }
    }

    // ---- MFMA: acc = NG@W + H@B (one 16-col slice per wave) ----
    const int w = t >> 6, l = t & 63;
    const int m16 = l & 15, quad = l >> 4;
    const int col = w * 16 + m16;

    short8 wfW[4], wfB[4];
#pragma unroll
    for (int q = 0; q < 4; ++q) {
        const int off = ((q * 4 + quad) * 128 + col) << 3;
        wfW[q] = *(const short8*)(pwW + off);
        wfB[q] = *(const short8*)(pwB + off);
    }

    f32x4 acc[4] = {};
#pragma unroll
    for (int q = 0; q < 4; ++q)
#pragma unroll
        for (int mt = 0; mt < 4; ++mt) {
            short8 aN = *(const short8*)(sng + (mt * 16 + m16) * LDP + q * 32 + quad * 8);
            short8 aH = *(const short8*)(sh  + (mt * 16 + m16) * LDP + q * 32 + quad * 8);
            acc[mt] = __builtin_amdgcn_mfma_f32_16x16x32_bf16(aN, wfW[q], acc[mt], 0, 0, 0);
            acc[mt] = __builtin_amdgcn_mfma_f32_16x16x32_bf16(aH, wfB[q], acc[mt], 0, 0, 0);
        }

#pragma unroll
    for (int mt = 0; mt < 4; ++mt)
#pragma unroll
        for (int r = 0; r < 4; ++r) {
            const int rr = row0 + mt * 16 + quad * 4 + r;
            h_out[(size_t)rr * HDIM + col] = __float2bfloat16(fmaxf(acc[mt][r], 0.0f));
        }
}

// ---------------- classifier: softmax(relu(h@W1+b1)@W2 + b2) ----------------
__global__ __launch_bounds__(512, 4) void cls_gemm(const bf16* __restrict__ h,
                                                   const short* __restrict__ pwW1,
                                                   const float* __restrict__ b1,
                                                   const short* __restrict__ pwW2,
                                                   const float* __restrict__ b2,
                                                   float* __restrict__ out) {
    __shared__ short sh[BM * LDP];
    __shared__ short sz[BM * LDP];
    __shared__ float lg[BM * 48];
    const int t = threadIdx.x;
    const int row0 = blockIdx.x * BM;

    {
        const int r = t >> 3, fs = (t & 7) * 16;
        const uint4* p = (const uint4*)(h + (size_t)(row0 + r) * HDIM + fs);
        uint4 a = p[0], b = p[1];
        uint4* d = (uint4*)(sh + r * LDP + fs);
        d[0] = a; d[1] = b;
    }
    __syncthreads();

    const int w = t >> 6, l = t & 63;
    const int m16 = l & 15, quad = l >> 4;
    const int col = w * 16 + m16;

    // ---- stage 1: z = relu(h @ W1 + b1) -> LDS ----
    {
        short8 wf[4];
#pragma unroll
        for (int q = 0; q < 4; ++q)
            wf[q] = *(const short8*)(pwW1 + (((q * 4 + quad) * 128 + col) << 3));
        f32x4 acc[4] = {};
#pragma unroll
        for (int q = 0; q < 4; ++q)
#pragma unroll
            for (int mt = 0; mt < 4; ++mt) {
                short8 a = *(const short8*)(sh + (mt * 16 + m16) * LDP + q * 32 + quad * 8);
                acc[mt] = __builtin_amdgcn_mfma_f32_16x16x32_bf16(a, wf[q], acc[mt], 0, 0, 0);
            }
        const float bias = b1[col];
#pragma unroll
        for (int mt = 0; mt < 4; ++mt)
#pragma unroll
            for (int r = 0; r < 4; ++r)
                sz[(mt * 16 + quad * 4 + r) * LDP + col] = f2bf(fmaxf(acc[mt][r] + bias, 0.0f));
    }
    __syncthreads();

    // ---- stage 2: logits = z @ W2 + b2 (waves 0..2 cover 40 cols) ----
    if (w < 3) {
        const bool valid = (col < NCLS);
        short8 wf[4];
#pragma unroll
        for (int q = 0; q < 4; ++q) {
            if (valid) wf[q] = *(const short8*)(pwW2 + (((q * 4 + quad) * NCLS + col) << 3));
            else {
#pragma unroll
                for (int j = 0; j < 8; ++j) wf[q][j] = 0;
            }
        }
        f32x4 acc[4] = {};
#pragma unroll
        for (int q = 0; q < 4; ++q)
#pragma unroll
            for (int mt = 0; mt < 4; ++mt) {
                short8 a = *(const short8*)(sz + (mt * 16 + m16) * LDP + q * 32 + quad * 8);
                acc[mt] = __builtin_amdgcn_mfma_f32_16x16x32_bf16(a, wf[q], acc[mt], 0, 0, 0);
            }
        if (valid) {
            const float bias = b2[col];
#pragma unroll
            for (int mt = 0; mt < 4; ++mt)
#pragma unroll
                for (int r = 0; r < 4; ++r)
                    lg[(mt * 16 + quad * 4 + r) * 48 + col] = acc[mt][r] + bias;
        }
    }
    __syncthreads();

    // ---- softmax per row ----
    if (t < BM) {
        float* row = lg + t * 48;
        float m = row[0];
        for (int c = 1; c < NCLS; ++c) m = fmaxf(m, row[c]);
        float s = 0.0f;
        for (int c = 0; c < NCLS; ++c) { float e = expf(row[c] - m); row[c] = e; s += e; }
        const float inv = 1.0f / s;
        for (int c = 0; c < NCLS; ++c) row[c] *= inv;
    }
    __syncthreads();

    for (int i = t; i < BM * NCLS; i += 512) {
        const int r = i / NCLS, c = i - r * NCLS;
        out[(size_t)row0 * NCLS + i] = lg[r * 48 + c];
    }
}

extern "C" void kernel_launch(void* const* d_in, const int* in_sizes, int n_in,
                              void* d_out, int out_size, void* d_ws, size_t ws_size,
                              hipStream_t stream) {
    const float* x    = (const float*)d_in[0];
    const int*  nidx  = (const int*)  d_in[1];
    const int*  vlen  = (const int*)  d_in[2];
    const float* Wemb = (const float*)d_in[3];
    const float* gW   = (const float*)d_in[4];
    const float* gB   = (const float*)d_in[5];
    const float* W1   = (const float*)d_in[6];
    const float* b1   = (const float*)d_in[7];
    const float* W2   = (const float*)d_in[8];
    const float* b2   = (const float*)d_in[9];
    float* out = (float*)d_out;

    const int nodes = BATCH * NB;           // 40000
    bf16* h0 = (bf16*)d_ws;
    bf16* h1 = h0 + (size_t)nodes * HDIM;
    short* pw = (short*)(h1 + (size_t)nodes * HDIM);   // 272 KB packed weights
    const short* pwE  = pw;
    const short* pwW1 = pw + 7 * 16384;
    const short* pwW2 = pw + 8 * 16384;

    pack_weights<<<(8 * 16384 + 128 * NCLS + 255) / 256, 256, 0, stream>>>(Wemb, gW, gB, W1, W2, pw);
    embed_gemm<<<NTILES, 512, 0, stream>>>(x, pwE, h0);

    for (int lyr = 0; lyr < NLAYER; ++lyr) {
        layer_gemm<<<LGRID, 512, 0, stream>>>(h0, nidx, vlen,
                                              pw + (size_t)(1 + lyr) * 16384,
                                              pw + (size_t)(4 + lyr) * 16384,
                                              h1);
        bf16* tmp = h0; h0 = h1; h1 = tmp;
    }

    cls_gemm<<<NTILES, 512, 0, stream>>>(h0, pwW1, b1, pwW2, b2, out);
}